// Round 5
// baseline (666.104 us; speedup 1.0000x reference)
//
#include <hip/hip_runtime.h>
#include <hip/hip_bf16.h>

#define NN 50000
#define EE 800000

typedef __attribute__((ext_vector_type(8))) short short8;
typedef __attribute__((ext_vector_type(4))) short short4v;
typedef __attribute__((ext_vector_type(4))) float f32x4;

__device__ __forceinline__ float bf2f(ushort u) {
  union { unsigned u; float f; } v; v.u = ((unsigned)u) << 16; return v.f;
}
__device__ __forceinline__ ushort f2bf(float f) {
  union { float f; unsigned u; } v; v.f = f;
  unsigned r = v.u + 0x7FFFu + ((v.u >> 16) & 1u);  // RNE
  return (ushort)(r >> 16);
}
__device__ __forceinline__ float silu(float v) {
  return v * __builtin_amdgcn_rcpf(1.f + __expf(-v));
}

// ---- merged prep: [hb convert] + weights->transposed bf16 + zero/init region ----
__global__ void prep_kernel(const float* __restrict__ h, ushort* __restrict__ hb,
                            const float* __restrict__ W1, const float* __restrict__ W2,
                            const float* __restrict__ W3,
                            ushort* __restrict__ W1t, ushort* __restrict__ W2t,
                            ushort* __restrict__ W3t,
                            int* __restrict__ zmem, int zval, int zcount, int hb_blocks) {
  int b = blockIdx.x, tid = threadIdx.x;
  if (b < hb_blocks) {                    // h -> hb, 8 elems/thread
    int i = b * 256 + tid;
    const float4* p = (const float4*)h;
    float4 a = p[2*i], c = p[2*i+1];
    short8 o;
    o[0]=f2bf(a.x); o[1]=f2bf(a.y); o[2]=f2bf(a.z); o[3]=f2bf(a.w);
    o[4]=f2bf(c.x); o[5]=f2bf(c.y); o[6]=f2bf(c.z); o[7]=f2bf(c.w);
    *(short8*)(hb + 8*i) = o;
  } else if (b < hb_blocks + 200) {       // weights
    int i = (b - hb_blocks) * 256 + tid;
    if (i < 32768) {                      // W1t [128 n][256 k]
      int n = i >> 8, k = i & 255;
      W1t[i] = f2bf(W1[k*128 + n]);
    } else if (i < 49152) {               // W2t [128 n][128 k]
      int j = i - 32768, n = j >> 7, k = j & 127;
      W2t[j] = f2bf(W2[k*128 + n]);
    } else if (i < 51200) {               // W3t [16 m][128 k], rows 9..15 zero
      int j = i - 49152, n = j >> 7, k = j & 127;
      W3t[j] = (n < 9) ? f2bf(W3[k*9 + n]) : (ushort)0;
    }
  } else {                                // init zmem
    int i = (b - hb_blocks - 200) * 256 + tid;
    if (i < zcount) zmem[i] = zval;
  }
}

// ---- linked-list CSR build: one int atomic per edge ----
__global__ void build_kernel(const int* __restrict__ row, int* __restrict__ head,
                             int* __restrict__ nxt) {
  int i = blockIdx.x * 256 + threadIdx.x;
  if (i < EE) nxt[i] = atomicExch(&head[row[i]], i);
}

// MODE: 0 = CSR output (trans_c writes, hb gather)
//       1 = atomic output, hb gather
//       2 = atomic output, f32 h gather
template<int MODE>
__global__ __launch_bounds__(256, 4)
void edge_kernel(const float* __restrict__ h, const ushort* __restrict__ hb,
                 const ushort* __restrict__ W1t, const ushort* __restrict__ W2t,
                 const ushort* __restrict__ W3t,
                 const float* __restrict__ W1,
                 const float* __restrict__ b1, const float* __restrict__ g1, const float* __restrict__ be1,
                 const float* __restrict__ b2, const float* __restrict__ g2, const float* __restrict__ be2,
                 const float* __restrict__ edge_attr, const float* __restrict__ edge_mask,
                 const float* __restrict__ coord_diff,
                 const int* __restrict__ row, const int* __restrict__ col,
                 float* __restrict__ agg, float* __restrict__ transc) {
  // LDS map (36864 B -> 4 blocks/CU):
  //  [0..32768)     smA [64 e][256 k] bf16 swizzled (gather; GEMM1 B). Dead after B2.
  //  [0..16384)     smX [64 e][128 n] bf16 swizzled (x1/x2) -- aliases smA.
  //  [16384..21504) smPhi [64 e][20] f32 -- aliases smA.
  //  [32768..35072) smCd [64][9] f32
  //  [35072..35840) smEA / smEM / smRow
  //  [35840..36864) smRed
  __shared__ __align__(16) char smem[36864];
  ushort* smA   = (ushort*)smem;
  ushort* smX   = (ushort*)smem;
  float*  smPhi = (float*)(smem + 16384);
  float*  smCd  = (float*)(smem + 32768);
  float*  smEA  = (float*)(smem + 35072);
  float*  smEM  = (float*)(smem + 35328);
  int*    smRow = (int*)  (smem + 35584);
  float2* smRed = (float2*)(smem + 35840);

  const int tid  = threadIdx.x;
  const int lane = tid & 63;
  const int w    = tid >> 6;
  const int l15  = lane & 15;
  const int lh   = lane >> 4;
  const int wm   = w >> 1;
  const int wn   = w & 1;
  const int e0   = blockIdx.x * 64;
  const int nb   = wm*64 + lh*4;

  // ---- gather A = [h[row] ++ h[col]] as bf16, swizzled ----
  {
    int e = tid >> 2, p = tid & 3;
    int re = row[e0 + e], ce = col[e0 + e];
    if (p == 0) { smEA[e] = edge_attr[e0+e]; smEM[e] = edge_mask[e0+e]; smRow[e] = re; }
    if (MODE < 2) {
      const ushort* s = hb + (size_t)((p & 2) ? ce : re) * 128 + (p & 1) * 64;
      #pragma unroll
      for (int c = 0; c < 8; ++c) {
        short8 v = *(const short8*)(s + c*8);
        int bo = (e*512 + (p*8 + c)*16) ^ ((e & 7) << 4);
        *(short8*)((char*)smA + bo) = v;
      }
    } else {
      const float* s = h + (size_t)((p & 2) ? ce : re) * 128 + (p & 1) * 64;
      #pragma unroll
      for (int c = 0; c < 8; ++c) {
        float4 a = *(const float4*)(s + c*8);
        float4 bq = *(const float4*)(s + c*8 + 4);
        short8 v;
        v[0]=f2bf(a.x); v[1]=f2bf(a.y); v[2]=f2bf(a.z); v[3]=f2bf(a.w);
        v[4]=f2bf(bq.x); v[5]=f2bf(bq.y); v[6]=f2bf(bq.z); v[7]=f2bf(bq.w);
        int bo = (e*512 + (p*8 + c)*16) ^ ((e & 7) << 4);
        *(short8*)((char*)smA + bo) = v;
      }
    }
  }
  if (tid < 144)
    *(float4*)(smCd + tid*4) = *(const float4*)(coord_diff + (size_t)e0*9 + tid*4);
  __syncthreads();                                   // B1

  // ---- GEMM1-T: out1T[n][e] = sum_k W1t[n][k] * A[e][k]   (K=256) ----
  f32x4 acc[4][2] = {};
  {
    const ushort* A0 = W1t + (size_t)(wm*64 + l15) * 256 + lh*8;
    #pragma unroll
    for (int k0 = 0; k0 < 8; ++k0) {
      short8 a[4], b[2];
      #pragma unroll
      for (int mf = 0; mf < 4; ++mf) a[mf] = *(const short8*)(A0 + mf*4096 + k0*32);
      #pragma unroll
      for (int nf = 0; nf < 2; ++nf) {
        int e = wn*32 + nf*16 + l15;
        int bo = (e*512 + k0*64 + lh*16) ^ ((e & 7) << 4);
        b[nf] = *(const short8*)((char*)smA + bo);
      }
      #pragma unroll
      for (int mf = 0; mf < 4; ++mf)
        #pragma unroll
        for (int nf = 0; nf < 2; ++nf)
          acc[mf][nf] = __builtin_amdgcn_mfma_f32_16x16x32_bf16(a[mf], b[nf], acc[mf][nf], 0, 0, 0);
    }
  }

  // ---- epi1 + LN1 stats in registers ----
  float s[2] = {0.f, 0.f}, q[2] = {0.f, 0.f};
  {
    const float* wl = W1 + 256*128;
    float ea[2];
    #pragma unroll
    for (int nf = 0; nf < 2; ++nf) ea[nf] = smEA[wn*32 + nf*16 + l15];
    #pragma unroll
    for (int mf = 0; mf < 4; ++mf) {
      float4 b1q = *(const float4*)(b1 + nb + mf*16);
      float4 wlq = *(const float4*)(wl + nb + mf*16);
      #pragma unroll
      for (int nf = 0; nf < 2; ++nf)
        #pragma unroll
        for (int j = 0; j < 4; ++j) {
          float t = acc[mf][nf][j] + ((const float*)&b1q)[j] + ea[nf] * ((const float*)&wlq)[j];
          acc[mf][nf][j] = t; s[nf] += t; q[nf] += t*t;
        }
    }
  }
  #pragma unroll
  for (int nf = 0; nf < 2; ++nf) {
    s[nf] += __shfl_xor(s[nf], 16, 64); s[nf] += __shfl_xor(s[nf], 32, 64);
    q[nf] += __shfl_xor(q[nf], 16, 64); q[nf] += __shfl_xor(q[nf], 32, 64);
  }
  if (lh == 0) {
    #pragma unroll
    for (int nf = 0; nf < 2; ++nf)
      smRed[((wm*2 + wn)*2 + nf)*16 + l15] = make_float2(s[nf], q[nf]);
  }
  __syncthreads();                                   // B2

  // ---- LN1 apply + SiLU -> smX ----
  {
    float m[2], rs[2];
    #pragma unroll
    for (int nf = 0; nf < 2; ++nf) {
      float2 po = smRed[(((wm^1)*2 + wn)*2 + nf)*16 + l15];
      float S = s[nf] + po.x, Q = q[nf] + po.y;
      m[nf] = S * (1.f/128.f);
      rs[nf] = rsqrtf(Q * (1.f/128.f) - m[nf]*m[nf] + 1e-5f);
    }
    #pragma unroll
    for (int mf = 0; mf < 4; ++mf) {
      float4 gq  = *(const float4*)(g1 + nb + mf*16);
      float4 beq = *(const float4*)(be1 + nb + mf*16);
      #pragma unroll
      for (int nf = 0; nf < 2; ++nf) {
        int e = wn*32 + nf*16 + l15;
        short4v o;
        #pragma unroll
        for (int j = 0; j < 4; ++j) {
          float val = (acc[mf][nf][j] - m[nf]) * rs[nf] * ((const float*)&gq)[j] + ((const float*)&beq)[j];
          o[j] = f2bf(silu(val));
        }
        int bo = (e*256 + (nb + mf*16)*2) ^ ((e & 7) << 4);
        *(short4v*)((char*)smX + bo) = o;
      }
    }
  }
  __syncthreads();                                   // B3

  // ---- GEMM2-T (K=128) ----
  f32x4 acc2[4][2] = {};
  {
    const ushort* A2 = W2t + (size_t)(wm*64 + l15) * 128 + lh*8;
    #pragma unroll
    for (int k0 = 0; k0 < 4; ++k0) {
      short8 a[4], b[2];
      #pragma unroll
      for (int mf = 0; mf < 4; ++mf) a[mf] = *(const short8*)(A2 + mf*2048 + k0*32);
      #pragma unroll
      for (int nf = 0; nf < 2; ++nf) {
        int e = wn*32 + nf*16 + l15;
        int bo = (e*256 + k0*64 + lh*16) ^ ((e & 7) << 4);
        b[nf] = *(const short8*)((char*)smX + bo);
      }
      #pragma unroll
      for (int mf = 0; mf < 4; ++mf)
        #pragma unroll
        for (int nf = 0; nf < 2; ++nf)
          acc2[mf][nf] = __builtin_amdgcn_mfma_f32_16x16x32_bf16(a[mf], b[nf], acc2[mf][nf], 0, 0, 0);
    }
  }

  // ---- epi2 + LN2 stats ----
  float s2[2] = {0.f, 0.f}, q2[2] = {0.f, 0.f};
  #pragma unroll
  for (int mf = 0; mf < 4; ++mf) {
    float4 b2q = *(const float4*)(b2 + nb + mf*16);
    #pragma unroll
    for (int nf = 0; nf < 2; ++nf)
      #pragma unroll
      for (int j = 0; j < 4; ++j) {
        float t = acc2[mf][nf][j] + ((const float*)&b2q)[j];
        acc2[mf][nf][j] = t; s2[nf] += t; q2[nf] += t*t;
      }
  }
  #pragma unroll
  for (int nf = 0; nf < 2; ++nf) {
    s2[nf] += __shfl_xor(s2[nf], 16, 64); s2[nf] += __shfl_xor(s2[nf], 32, 64);
    q2[nf] += __shfl_xor(q2[nf], 16, 64); q2[nf] += __shfl_xor(q2[nf], 32, 64);
  }
  if (lh == 0) {
    #pragma unroll
    for (int nf = 0; nf < 2; ++nf)
      smRed[((wm*2 + wn)*2 + nf)*16 + l15] = make_float2(s2[nf], q2[nf]);
  }
  __syncthreads();                                   // B4

  // ---- LN2 + SiLU -> smX in place ----
  {
    float m[2], rs[2];
    #pragma unroll
    for (int nf = 0; nf < 2; ++nf) {
      float2 po = smRed[(((wm^1)*2 + wn)*2 + nf)*16 + l15];
      float S = s2[nf] + po.x, Q = q2[nf] + po.y;
      m[nf] = S * (1.f/128.f);
      rs[nf] = rsqrtf(Q * (1.f/128.f) - m[nf]*m[nf] + 1e-5f);
    }
    #pragma unroll
    for (int mf = 0; mf < 4; ++mf) {
      float4 gq  = *(const float4*)(g2 + nb + mf*16);
      float4 beq = *(const float4*)(be2 + nb + mf*16);
      #pragma unroll
      for (int nf = 0; nf < 2; ++nf) {
        int e = wn*32 + nf*16 + l15;
        short4v o;
        #pragma unroll
        for (int j = 0; j < 4; ++j) {
          float val = (acc2[mf][nf][j] - m[nf]) * rs[nf] * ((const float*)&gq)[j] + ((const float*)&beq)[j];
          o[j] = f2bf(silu(val));
        }
        int bo = (e*256 + (nb + mf*16)*2) ^ ((e & 7) << 4);
        *(short4v*)((char*)smX + bo) = o;
      }
    }
  }
  __syncthreads();                                   // B5

  // ---- GEMM3-T: phiT[m3][e]; wave w owns e = w*16+l15 ----
  {
    f32x4 acc3 = {};
    const ushort* A3 = W3t + (size_t)l15 * 128 + lh*8;
    int e = w*16 + l15;
    #pragma unroll
    for (int k0 = 0; k0 < 4; ++k0) {
      short8 a = *(const short8*)(A3 + k0*32);
      int bo = (e*256 + k0*64 + lh*16) ^ ((e & 7) << 4);
      short8 b = *(const short8*)((char*)smX + bo);
      acc3 = __builtin_amdgcn_mfma_f32_16x16x32_bf16(a, b, acc3, 0, 0, 0);
    }
    *(float4*)(smPhi + e*20 + lh*4) = *(float4*)&acc3;
  }
  __syncthreads();                                   // B6

  // ---- trans[l][k] = sum_j cd[j][k]*phi[j*?]; output ----
  if (MODE == 0) {
    // coalesced slice-major write: trans_c[c][e0+e]
    #pragma unroll
    for (int it = 0; it < 3; ++it) {
      int idx = it*256 + tid;
      if (idx < 576) {
        int c = idx >> 6, e = idx & 63;
        int l2 = c / 3, k = c - l2*3;
        const float* cd = smCd + e*9;
        const float* ph = smPhi + e*20;
        float t = cd[k]*ph[l2] + cd[3+k]*ph[3+l2] + cd[6+k]*ph[6+l2];
        transc[(size_t)c*EE + e0 + e] = t * smEM[e];
      }
    }
  } else {
    int e = tid >> 2, qd = tid & 3;
    int re = smRow[e];
    float em = smEM[e];
    const float* cd = smCd + e*9;
    const float* ph = smPhi + e*20;
    for (int idx = qd; idx < 9; idx += 4) {
      int l2 = idx / 3, k = idx - l2*3;
      float t = cd[k]*ph[l2] + cd[3+k]*ph[3+l2] + cd[6+k]*ph[6+l2];
      unsafeAtomicAdd(&agg[(size_t)re*9 + idx], t * em);
    }
  }
}

// ---- gather: thread per (c, n); walk node's edge list, sum slice c ----
__global__ void gather_kernel(const float* __restrict__ coord, const float* __restrict__ node_mask,
                              const float* __restrict__ transc, const int* __restrict__ head,
                              const int* __restrict__ nxt, float* __restrict__ out) {
  int i = blockIdx.x * 256 + threadIdx.x;
  if (i >= 9*NN) return;
  int c = i / NN;
  int n = i - c*NN;
  const float* slice = transc + (size_t)c*EE;
  float sum = 0.f;
  for (int e = head[n]; e >= 0; e = nxt[e]) sum += slice[e];
  out[n*9 + c] = (coord[n*9 + c] + sum * 0.01f) * node_mask[n];
}

__global__ void finalize_kernel(const float* __restrict__ coord, const float* __restrict__ node_mask,
                                const float* __restrict__ agg, float* __restrict__ out) {
  int i = blockIdx.x * 256 + threadIdx.x;
  if (i < NN*9) {
    int n = i / 9;
    out[i] = (coord[i] + agg[i] * 0.01f) * node_mask[n];
  }
}

extern "C" void kernel_launch(void* const* d_in, const int* in_sizes, int n_in,
                              void* d_out, int out_size, void* d_ws, size_t ws_size,
                              hipStream_t stream) {
  const float* h          = (const float*)d_in[0];
  const float* coord      = (const float*)d_in[1];
  const float* coord_diff = (const float*)d_in[2];
  const float* edge_attr  = (const float*)d_in[3];
  const float* edge_mask  = (const float*)d_in[4];
  const float* node_mask  = (const float*)d_in[5];
  const int*   rowi       = (const int*)d_in[6];
  const int*   coli       = (const int*)d_in[7];
  const float* W1  = (const float*)d_in[8];
  const float* b1  = (const float*)d_in[9];
  const float* g1  = (const float*)d_in[10];
  const float* be1 = (const float*)d_in[11];
  const float* W2  = (const float*)d_in[12];
  const float* b2  = (const float*)d_in[13];
  const float* g2  = (const float*)d_in[14];
  const float* be2 = (const float*)d_in[15];
  const float* W3  = (const float*)d_in[16];

  char* ws = (char*)d_ws;
  const size_t needA = 45102400;                     // CSR mode
  const size_t needB = (size_t)1902464 + 12800000;   // atomic + hb
  if (ws_size >= needA) {
    float* transc = (float*)ws;                      // 28,800,000
    int*   head   = (int*)(ws + 28800000);           // 200,000
    int*   nxt    = (int*)(ws + 29000000);           // 3,200,000
    ushort* W1t   = (ushort*)(ws + 32200000);        // 65,536
    ushort* W2t   = (ushort*)(ws + 32265536);        // 32,768
    ushort* W3t   = (ushort*)(ws + 32298304);        // 4,096
    ushort* hb    = (ushort*)(ws + 32302400);        // 12,800,000
    prep_kernel<<<3125 + 200 + 196, 256, 0, stream>>>(h, hb, W1, W2, W3, W1t, W2t, W3t,
                                                      head, -1, NN, 3125);
    build_kernel<<<EE/256, 256, 0, stream>>>(rowi, head, nxt);
    edge_kernel<0><<<EE/64, 256, 0, stream>>>(h, hb, W1t, W2t, W3t, W1,
        b1, g1, be1, b2, g2, be2, edge_attr, edge_mask, coord_diff, rowi, coli,
        nullptr, transc);
    gather_kernel<<<(9*NN + 255)/256, 256, 0, stream>>>(coord, node_mask, transc, head, nxt,
                                                        (float*)d_out);
  } else if (ws_size >= needB) {
    float*  agg = (float*)ws;                        // 1,800,000 (+pad)
    ushort* W1t = (ushort*)(ws + 1800064);
    ushort* W2t = (ushort*)(ws + 1865600);
    ushort* W3t = (ushort*)(ws + 1898368);
    ushort* hb  = (ushort*)(ws + 1902464);
    prep_kernel<<<3125 + 200 + 1758, 256, 0, stream>>>(h, hb, W1, W2, W3, W1t, W2t, W3t,
                                                       (int*)agg, 0, NN*9, 3125);
    edge_kernel<1><<<EE/64, 256, 0, stream>>>(h, hb, W1t, W2t, W3t, W1,
        b1, g1, be1, b2, g2, be2, edge_attr, edge_mask, coord_diff, rowi, coli,
        agg, nullptr);
    finalize_kernel<<<(NN*9 + 255)/256, 256, 0, stream>>>(coord, node_mask, agg, (float*)d_out);
  } else {
    float*  agg = (float*)ws;
    ushort* W1t = (ushort*)(ws + 1800064);
    ushort* W2t = (ushort*)(ws + 1865600);
    ushort* W3t = (ushort*)(ws + 1898368);
    prep_kernel<<<200 + 1758, 256, 0, stream>>>(h, nullptr, W1, W2, W3, W1t, W2t, W3t,
                                                (int*)agg, 0, NN*9, 0);
    edge_kernel<2><<<EE/64, 256, 0, stream>>>(h, nullptr, W1t, W2t, W3t, W1,
        b1, g1, be1, b2, g2, be2, edge_attr, edge_mask, coord_diff, rowi, coli,
        agg, nullptr);
    finalize_kernel<<<(NN*9 + 255)/256, 256, 0, stream>>>(coord, node_mask, agg, (float*)d_out);
  }
}

// Round 7
// 536.264 us; speedup vs baseline: 1.2421x; 1.2421x over previous
//
#include <hip/hip_runtime.h>
#include <hip/hip_bf16.h>

#define NN 50000
#define EE 800000

typedef __attribute__((ext_vector_type(8))) short short8;
typedef __attribute__((ext_vector_type(4))) short short4v;
typedef __attribute__((ext_vector_type(4))) float f32x4;

__device__ __forceinline__ float bf2f(ushort u) {
  union { unsigned u; float f; } v; v.u = ((unsigned)u) << 16; return v.f;
}
__device__ __forceinline__ ushort f2bf(float f) {
  union { float f; unsigned u; } v; v.f = f;
  unsigned r = v.u + 0x7FFFu + ((v.u >> 16) & 1u);  // RNE
  return (ushort)(r >> 16);
}
__device__ __forceinline__ float silu(float v) {
  return v * __builtin_amdgcn_rcpf(1.f + __expf(-v));
}

// ---- prep: weight transposes (bf16) + agg zeroing ----
__global__ void prep_kernel(const float* __restrict__ W1, const float* __restrict__ W2,
                            const float* __restrict__ W3,
                            ushort* __restrict__ W1at, ushort* __restrict__ W1bt,
                            ushort* __restrict__ W2t, ushort* __restrict__ W3t,
                            float* __restrict__ agg) {
  int b = blockIdx.x, tid = threadIdx.x;
  if (b < 200) {                          // weights
    int i = b * 256 + tid;
    if (i < 16384) {                      // W1at [128 n][128 k] = W1[k][n], k<128
      int n = i >> 7, k = i & 127;
      W1at[i] = f2bf(W1[k*128 + n]);
    } else if (i < 32768) {               // W1bt = W1[k+128][n]
      int j = i - 16384, n = j >> 7, k = j & 127;
      W1bt[j] = f2bf(W1[(k + 128)*128 + n]);
    } else if (i < 49152) {               // W2t [128 n][128 k]
      int j = i - 32768, n = j >> 7, k = j & 127;
      W2t[j] = f2bf(W2[k*128 + n]);
    } else if (i < 51200) {               // W3t [16 m][128 k], rows 9..15 zero
      int j = i - 49152, n = j >> 7, k = j & 127;
      W3t[j] = (n < 9) ? f2bf(W3[k*9 + n]) : (ushort)0;
    }
  } else {                                // zero agg
    int i = (b - 200) * 256 + tid;
    if (i < NN*9) agg[i] = 0.f;
  }
}

// ---- node kernel: P = h@W1a + b1, Q = h@W1b  (per 64-node tile) ----
template<bool PQF32>
__global__ __launch_bounds__(256, 4)
void node_kernel(const float* __restrict__ h,
                 const ushort* __restrict__ W1at, const ushort* __restrict__ W1bt,
                 const float* __restrict__ b1,
                 void* __restrict__ Pv, void* __restrict__ Qv) {
  __shared__ __align__(16) ushort smH[64*128];      // 16 KB, swizzled
  const int tid = threadIdx.x;
  const int lane = tid & 63;
  const int w   = tid >> 6;
  const int l15 = lane & 15;
  const int lh  = lane >> 4;
  const int wm  = w >> 1;       // 0 -> P (W1at), 1 -> Q (W1bt)
  const int wn  = w & 1;        // node half
  const int n0  = blockIdx.x * 64;

  {   // stage h tile (coalesced), convert to bf16, swizzle
    int e = tid >> 2, p = tid & 3;
    int nn = n0 + e; if (nn >= NN) nn = NN - 1;
    const float* s = h + (size_t)nn*128 + p*32;
    #pragma unroll
    for (int c = 0; c < 4; ++c) {
      float4 a = *(const float4*)(s + c*8);
      float4 bq = *(const float4*)(s + c*8 + 4);
      short8 v;
      v[0]=f2bf(a.x); v[1]=f2bf(a.y); v[2]=f2bf(a.z); v[3]=f2bf(a.w);
      v[4]=f2bf(bq.x); v[5]=f2bf(bq.y); v[6]=f2bf(bq.z); v[7]=f2bf(bq.w);
      int bo = (e*256 + p*64 + c*16) ^ ((e & 7) << 4);
      *(short8*)((char*)smH + bo) = v;
    }
  }
  __syncthreads();

  const ushort* W = wm ? W1bt : W1at;
  f32x4 acc[4][2] = {};
  #pragma unroll
  for (int k0 = 0; k0 < 4; ++k0) {
    short8 a[4], b[2];
    #pragma unroll
    for (int mf = 0; mf < 4; ++mf)
      a[mf] = *(const short8*)(W + (size_t)(mf*16 + l15)*128 + k0*32 + lh*8);
    #pragma unroll
    for (int nf = 0; nf < 2; ++nf) {
      int e = wn*32 + nf*16 + l15;
      int bo = (e*256 + k0*64 + lh*16) ^ ((e & 7) << 4);
      b[nf] = *(const short8*)((char*)smH + bo);
    }
    #pragma unroll
    for (int mf = 0; mf < 4; ++mf)
      #pragma unroll
      for (int nf = 0; nf < 2; ++nf)
        acc[mf][nf] = __builtin_amdgcn_mfma_f32_16x16x32_bf16(a[mf], b[nf], acc[mf][nf], 0, 0, 0);
  }

  #pragma unroll
  for (int mf = 0; mf < 4; ++mf) {
    float4 bq = *(const float4*)(b1 + mf*16 + lh*4);
    #pragma unroll
    for (int nf = 0; nf < 2; ++nf) {
      int node = n0 + wn*32 + nf*16 + l15;
      if (node < NN) {
        f32x4 r = acc[mf][nf];
        if (wm == 0) { r[0]+=bq.x; r[1]+=bq.y; r[2]+=bq.z; r[3]+=bq.w; }
        if (PQF32) {
          float* dst = (float*)(wm ? Qv : Pv) + (size_t)node*128 + mf*16 + lh*4;
          *(f32x4*)dst = r;
        } else {
          ushort* dst = (ushort*)(wm ? Qv : Pv) + (size_t)node*128 + mf*16 + lh*4;
          short4v o; o[0]=f2bf(r[0]); o[1]=f2bf(r[1]); o[2]=f2bf(r[2]); o[3]=f2bf(r[3]);
          *(short4v*)dst = o;
        }
      }
    }
  }
}

// ---- edge kernel: x1 = LN(P[row]+Q[col]+ea*wl) in registers; GEMM2; GEMM3; scatter ----
template<bool PQF32>
__global__ __launch_bounds__(256, 6)
void edge_kernel(const void* __restrict__ Pv, const void* __restrict__ Qv,
                 const float* __restrict__ w1last,
                 const float* __restrict__ g1, const float* __restrict__ be1,
                 const ushort* __restrict__ W2t, const ushort* __restrict__ W3t,
                 const float* __restrict__ b2, const float* __restrict__ g2, const float* __restrict__ be2,
                 const float* __restrict__ edge_attr, const float* __restrict__ edge_mask,
                 const float* __restrict__ coord_diff,
                 const int* __restrict__ row, const int* __restrict__ col,
                 float* __restrict__ agg) {
  // LDS: smX 16384 | smPhi 5120 | smCd 2304 | smRed 1024 | smEM 256 | smRow 256 = 25344 B
  __shared__ __align__(16) char smem[25344];
  ushort* smX   = (ushort*)smem;
  float*  smPhi = (float*)(smem + 16384);
  float*  smCd  = (float*)(smem + 21504);
  float2* smRed = (float2*)(smem + 23808);
  float*  smEM  = (float*)(smem + 24832);
  int*    smRow = (int*)  (smem + 25088);

  const int tid  = threadIdx.x;
  const int lane = tid & 63;
  const int w    = tid >> 6;
  const int l15  = lane & 15;
  const int lh   = lane >> 4;
  const int wm   = w >> 1;
  const int wn   = w & 1;
  const int e0   = blockIdx.x * 64;
  const int nb   = wm*64 + lh*4;

  // ---- phase 1: x1 pre-LN in registers, LN1 via 4-lane shfl, SiLU -> smX ----
  {
    int e = tid >> 2, p = tid & 3;
    int re = row[e0 + e], ce = col[e0 + e];
    float ea = edge_attr[e0 + e];
    if (p == 0) { smEM[e] = edge_mask[e0+e]; smRow[e] = re; }

    float v[32]; float s = 0.f, q = 0.f;
    if (PQF32) {
      const float* Pp = (const float*)Pv + (size_t)re*128 + p*32;
      const float* Qp = (const float*)Qv + (size_t)ce*128 + p*32;
      #pragma unroll
      for (int c = 0; c < 8; ++c) {
        float4 a = *(const float4*)(Pp + c*4);
        float4 bq = *(const float4*)(Qp + c*4);
        float4 wq = *(const float4*)(w1last + p*32 + c*4);
        #pragma unroll
        for (int j = 0; j < 4; ++j) {
          float t = ((const float*)&a)[j] + ((const float*)&bq)[j] + ea * ((const float*)&wq)[j];
          v[c*4 + j] = t; s += t; q += t*t;
        }
      }
    } else {
      const ushort* Pp = (const ushort*)Pv + (size_t)re*128 + p*32;
      const ushort* Qp = (const ushort*)Qv + (size_t)ce*128 + p*32;
      #pragma unroll
      for (int c = 0; c < 4; ++c) {
        short8 a = *(const short8*)(Pp + c*8);
        short8 bq = *(const short8*)(Qp + c*8);
        float4 wq0 = *(const float4*)(w1last + p*32 + c*8);
        float4 wq1 = *(const float4*)(w1last + p*32 + c*8 + 4);
        #pragma unroll
        for (int j = 0; j < 8; ++j) {
          float wv = (j < 4) ? ((const float*)&wq0)[j] : ((const float*)&wq1)[j-4];
          float t = bf2f((ushort)a[j]) + bf2f((ushort)bq[j]) + ea * wv;
          v[c*8 + j] = t; s += t; q += t*t;
        }
      }
    }
    s += __shfl_xor(s, 1, 64); s += __shfl_xor(s, 2, 64);
    q += __shfl_xor(q, 1, 64); q += __shfl_xor(q, 2, 64);
    float m  = s * (1.f/128.f);
    float rs = rsqrtf(q * (1.f/128.f) - m*m + 1e-5f);
    #pragma unroll
    for (int c = 0; c < 4; ++c) {
      float4 gq0 = *(const float4*)(g1 + p*32 + c*8);
      float4 gq1 = *(const float4*)(g1 + p*32 + c*8 + 4);
      float4 bq0 = *(const float4*)(be1 + p*32 + c*8);
      float4 bq1 = *(const float4*)(be1 + p*32 + c*8 + 4);
      short8 o;
      #pragma unroll
      for (int j = 0; j < 8; ++j) {
        float gv = (j < 4) ? ((const float*)&gq0)[j] : ((const float*)&gq1)[j-4];
        float bv = (j < 4) ? ((const float*)&bq0)[j] : ((const float*)&bq1)[j-4];
        float val = (v[c*8+j] - m) * rs * gv + bv;
        o[j] = f2bf(silu(val));
      }
      int bo = (e*256 + p*64 + c*16) ^ ((e & 7) << 4);
      *(short8*)((char*)smX + bo) = o;
    }
  }
  if (tid < 144)
    *(float4*)(smCd + tid*4) = *(const float4*)(coord_diff + (size_t)e0*9 + tid*4);
  __syncthreads();                                   // B1 (x1 ready)

  // ---- GEMM2-T: out2T[n][e] = sum_k W2t[n][k] * x1[e][k] ----
  f32x4 acc2[4][2] = {};
  {
    const ushort* A2 = W2t + (size_t)(wm*64 + l15) * 128 + lh*8;
    #pragma unroll
    for (int k0 = 0; k0 < 4; ++k0) {
      short8 a[4], b[2];
      #pragma unroll
      for (int mf = 0; mf < 4; ++mf) a[mf] = *(const short8*)(A2 + mf*2048 + k0*32);
      #pragma unroll
      for (int nf = 0; nf < 2; ++nf) {
        int e = wn*32 + nf*16 + l15;
        int bo = (e*256 + k0*64 + lh*16) ^ ((e & 7) << 4);
        b[nf] = *(const short8*)((char*)smX + bo);
      }
      #pragma unroll
      for (int mf = 0; mf < 4; ++mf)
        #pragma unroll
        for (int nf = 0; nf < 2; ++nf)
          acc2[mf][nf] = __builtin_amdgcn_mfma_f32_16x16x32_bf16(a[mf], b[nf], acc2[mf][nf], 0, 0, 0);
    }
  }

  // ---- epi2 + LN2 stats ----
  float s2[2] = {0.f, 0.f}, q2[2] = {0.f, 0.f};
  #pragma unroll
  for (int mf = 0; mf < 4; ++mf) {
    float4 b2q = *(const float4*)(b2 + nb + mf*16);
    #pragma unroll
    for (int nf = 0; nf < 2; ++nf)
      #pragma unroll
      for (int j = 0; j < 4; ++j) {
        float t = acc2[mf][nf][j] + ((const float*)&b2q)[j];
        acc2[mf][nf][j] = t; s2[nf] += t; q2[nf] += t*t;
      }
  }
  #pragma unroll
  for (int nf = 0; nf < 2; ++nf) {
    s2[nf] += __shfl_xor(s2[nf], 16, 64); s2[nf] += __shfl_xor(s2[nf], 32, 64);
    q2[nf] += __shfl_xor(q2[nf], 16, 64); q2[nf] += __shfl_xor(q2[nf], 32, 64);
  }
  if (lh == 0) {
    #pragma unroll
    for (int nf = 0; nf < 2; ++nf)
      smRed[((wm*2 + wn)*2 + nf)*16 + l15] = make_float2(s2[nf], q2[nf]);
  }
  __syncthreads();                                   // B2 (partials visible; x1 reads done)

  // ---- LN2 + SiLU -> smX in place ----
  {
    float m[2], rs[2];
    #pragma unroll
    for (int nf = 0; nf < 2; ++nf) {
      float2 po = smRed[(((wm^1)*2 + wn)*2 + nf)*16 + l15];
      float S = s2[nf] + po.x, Q = q2[nf] + po.y;
      m[nf] = S * (1.f/128.f);
      rs[nf] = rsqrtf(Q * (1.f/128.f) - m[nf]*m[nf] + 1e-5f);
    }
    #pragma unroll
    for (int mf = 0; mf < 4; ++mf) {
      float4 gq  = *(const float4*)(g2 + nb + mf*16);
      float4 beq = *(const float4*)(be2 + nb + mf*16);
      #pragma unroll
      for (int nf = 0; nf < 2; ++nf) {
        int e = wn*32 + nf*16 + l15;
        short4v o;
        #pragma unroll
        for (int j = 0; j < 4; ++j) {
          float val = (acc2[mf][nf][j] - m[nf]) * rs[nf] * ((const float*)&gq)[j] + ((const float*)&beq)[j];
          o[j] = f2bf(silu(val));
        }
        int bo = (e*256 + (nb + mf*16)*2) ^ ((e & 7) << 4);
        *(short4v*)((char*)smX + bo) = o;
      }
    }
  }
  __syncthreads();                                   // B3 (x2 ready)

  // ---- GEMM3-T: phiT[m3][e]; wave w owns e = w*16+l15 ----
  {
    f32x4 acc3 = {};
    const ushort* A3 = W3t + (size_t)l15 * 128 + lh*8;
    int e = w*16 + l15;
    #pragma unroll
    for (int k0 = 0; k0 < 4; ++k0) {
      short8 a = *(const short8*)(A3 + k0*32);
      int bo = (e*256 + k0*64 + lh*16) ^ ((e & 7) << 4);
      short8 b = *(const short8*)((char*)smX + bo);
      acc3 = __builtin_amdgcn_mfma_f32_16x16x32_bf16(a, b, acc3, 0, 0, 0);
    }
    *(float4*)(smPhi + e*20 + lh*4) = *(float4*)&acc3;
  }
  __syncthreads();                                   // B4 (phi ready)

  // ---- trans + scatter-add ----
  {
    int e = tid >> 2, qd = tid & 3;
    int re = smRow[e];
    float em = smEM[e];
    const float* cd = smCd + e*9;
    const float* ph = smPhi + e*20;
    for (int idx = qd; idx < 9; idx += 4) {
      int l2 = idx / 3, k = idx - l2*3;
      float t = cd[k]*ph[l2] + cd[3+k]*ph[3+l2] + cd[6+k]*ph[6+l2];
      unsafeAtomicAdd(&agg[(size_t)re*9 + idx], t * em);
    }
  }
}

__global__ void finalize_kernel(const float* __restrict__ coord, const float* __restrict__ node_mask,
                                const float* __restrict__ agg, float* __restrict__ out) {
  int i = blockIdx.x * 256 + threadIdx.x;
  if (i < NN*9) {
    int n = i / 9;
    out[i] = (coord[i] + agg[i] * 0.01f) * node_mask[n];
  }
}

extern "C" void kernel_launch(void* const* d_in, const int* in_sizes, int n_in,
                              void* d_out, int out_size, void* d_ws, size_t ws_size,
                              hipStream_t stream) {
  const float* h          = (const float*)d_in[0];
  const float* coord      = (const float*)d_in[1];
  const float* coord_diff = (const float*)d_in[2];
  const float* edge_attr  = (const float*)d_in[3];
  const float* edge_mask  = (const float*)d_in[4];
  const float* node_mask  = (const float*)d_in[5];
  const int*   rowi       = (const int*)d_in[6];
  const int*   coli       = (const int*)d_in[7];
  const float* W1  = (const float*)d_in[8];
  const float* b1  = (const float*)d_in[9];
  const float* g1  = (const float*)d_in[10];
  const float* be1 = (const float*)d_in[11];
  const float* W2  = (const float*)d_in[12];
  const float* b2  = (const float*)d_in[13];
  const float* g2  = (const float*)d_in[14];
  const float* be2 = (const float*)d_in[15];
  const float* W3  = (const float*)d_in[16];
  const float* w1last = W1 + 256*128;

  char* ws = (char*)d_ws;
  const size_t needF32 = 53102400;
  const int nodeBlocks = (NN + 63) / 64;             // 782
  const int aggBlocks  = (NN*9 + 255) / 256;         // 1758

  if (ws_size >= needF32) {
    float*  P    = (float*)ws;                       // 25,600,000
    float*  Q    = (float*)(ws + 25600000);          // 25,600,000
    float*  agg  = (float*)(ws + 51200000);          // 1,800,000
    ushort* W1at = (ushort*)(ws + 53000000);         // 32,768
    ushort* W1bt = (ushort*)(ws + 53032768);         // 32,768
    ushort* W2t  = (ushort*)(ws + 53065536);         // 32,768
    ushort* W3t  = (ushort*)(ws + 53098304);         // 4,096
    prep_kernel<<<200 + aggBlocks, 256, 0, stream>>>(W1, W2, W3, W1at, W1bt, W2t, W3t, agg);
    node_kernel<true><<<nodeBlocks, 256, 0, stream>>>(h, W1at, W1bt, b1, P, Q);
    edge_kernel<true><<<EE/64, 256, 0, stream>>>(P, Q, w1last, g1, be1, W2t, W3t,
        b2, g2, be2, edge_attr, edge_mask, coord_diff, rowi, coli, agg);
    finalize_kernel<<<aggBlocks, 256, 0, stream>>>(coord, node_mask, agg, (float*)d_out);
  } else {
    ushort* P    = (ushort*)ws;                      // 12,800,000
    ushort* Q    = (ushort*)(ws + 12800000);         // 12,800,000
    float*  agg  = (float*)(ws + 25600000);          // 1,800,000
    ushort* W1at = (ushort*)(ws + 27400000);
    ushort* W1bt = (ushort*)(ws + 27432768);
    ushort* W2t  = (ushort*)(ws + 27465536);
    ushort* W3t  = (ushort*)(ws + 27498304);
    prep_kernel<<<200 + aggBlocks, 256, 0, stream>>>(W1, W2, W3, W1at, W1bt, W2t, W3t, agg);
    node_kernel<false><<<nodeBlocks, 256, 0, stream>>>(h, W1at, W1bt, b1, P, Q);
    edge_kernel<false><<<EE/64, 256, 0, stream>>>(P, Q, w1last, g1, be1, W2t, W3t,
        b2, g2, be2, edge_attr, edge_mask, coord_diff, rowi, coli, agg);
    finalize_kernel<<<aggBlocks, 256, 0, stream>>>(coord, node_mask, agg, (float*)d_out);
  }
}